// Round 1
// baseline (4332.146 us; speedup 1.0000x reference)
//
#include <hip/hip_runtime.h>
#include <math.h>

// ---------------- problem constants ----------------
#define N_TOK 8192              // L*B
#define D_DIM 1024
#define F_DIM 4096
#define E_NUM 8
#define NP    16384             // N_TOK * K(=2)
#define TM    128               // token-tile (pad granularity)
#define PAD_CAP (NP + E_NUM*TM) // 17408
#define MAX_TILES (PAD_CAP/TM)  // 136

// ---------------- workspace layout ----------------
struct Ws {
  float glTask[E_NUM];     // task-gate logits
  float Sw[E_NUM];         // sum of full softmax weights per expert
  float Sc[E_NUM];         // sum of selection counts per expert
  int   cnt[E_NUM];        // tokens routed to each expert
  int   cursor[E_NUM];     // scatter cursors
  int   pad_off[E_NUM+1];  // padded row offsets (multiples of TM)
  int   ntiles;
  int   tile_expert[MAX_TILES];
  int   sel[NP];           // per-token selected experts (2 each)
  float wsel[NP];          // per-token combine weights (2 each)
  int   perm_token[PAD_CAP]; // padded permutation: token id or -1
  float perm_w[PAD_CAP];     // combine weight per padded slot
};
// hbuf (fp32 [tiles*TM x F]) lives after Ws, 256-aligned, chunked by ws_size.

__device__ __forceinline__ float silu_f(float x) { return x / (1.f + expf(-x)); }

// ---------------- setup: task gate + zero accumulators ----------------
__global__ void setup_kernel(const float* __restrict__ task_param,
                             const float* __restrict__ Wg_task,
                             const float* __restrict__ bg_task,
                             Ws* __restrict__ ws) {
  __shared__ float part[32][E_NUM];
  const int t = threadIdx.x;
  const int e = t & 7, ch = t >> 3;          // 32 chunks x 8 experts
  float s = 0.f;
  for (int d = ch*32; d < ch*32 + 32; ++d) s += task_param[d] * Wg_task[d*E_NUM + e];
  part[ch][e] = s;
  __syncthreads();
  for (int str = 16; str > 0; str >>= 1) {
    if (ch < str) part[ch][e] += part[ch+str][e];
    __syncthreads();
  }
  if (t < E_NUM) {
    ws->glTask[t] = part[0][t] + bg_task[t];
    ws->Sw[t] = 0.f; ws->Sc[t] = 0.f; ws->cnt[t] = 0;
  }
}

// ---------------- gating: logits, softmax stats, top-2 ----------------
__global__ __launch_bounds__(256) void gate_kernel(const float* __restrict__ X,
                                                   const float* __restrict__ Wg_in,
                                                   const float* __restrict__ bg_in,
                                                   const float* __restrict__ alpha_p,
                                                   Ws* __restrict__ ws) {
  __shared__ float swL[E_NUM];
  __shared__ float scL[E_NUM];
  __shared__ int   cntL[E_NUM];
  const int t = threadIdx.x;
  if (t < E_NUM) { swL[t] = 0.f; scL[t] = 0.f; cntL[t] = 0; }
  __syncthreads();
  const int lane = t & 63, wv = t >> 6;
  const int n = blockIdx.x * 4 + wv;         // one wave per token
  const float* xr = X + (size_t)n * D_DIM;

  float acc[E_NUM] = {0.f,0.f,0.f,0.f,0.f,0.f,0.f,0.f};
  #pragma unroll
  for (int it = 0; it < 4; ++it) {
    const int d0 = it*256 + lane*4;
    const float4 x4 = *(const float4*)(xr + d0);
    const float xs[4] = {x4.x, x4.y, x4.z, x4.w};
    #pragma unroll
    for (int j = 0; j < 4; ++j) {
      const float* wr = Wg_in + (size_t)(d0 + j) * E_NUM;
      const float4 wa = *(const float4*)(wr);
      const float4 wb = *(const float4*)(wr + 4);
      acc[0] += xs[j]*wa.x; acc[1] += xs[j]*wa.y; acc[2] += xs[j]*wa.z; acc[3] += xs[j]*wa.w;
      acc[4] += xs[j]*wb.x; acc[5] += xs[j]*wb.y; acc[6] += xs[j]*wb.z; acc[7] += xs[j]*wb.w;
    }
  }
  #pragma unroll
  for (int e = 0; e < E_NUM; ++e) {
    #pragma unroll
    for (int m = 1; m < 64; m <<= 1) acc[e] += __shfl_xor(acc[e], m, 64);
  }

  if (lane == 0) {
    const float a = *alpha_p;
    float lg[E_NUM];
    #pragma unroll
    for (int e = 0; e < E_NUM; ++e) {
      float v = (1.f - a) * (acc[e] + bg_in[e]) + a * ws->glTask[e];
      const unsigned u = __float_as_uint(v);
      if ((u & 0x7f800000u) == 0x7f800000u) v = 0.f;   // nan_to_num (nan/±inf -> 0)
      lg[e] = v;
    }
    float mx = lg[0];
    #pragma unroll
    for (int e = 1; e < E_NUM; ++e) mx = fmaxf(mx, lg[e]);
    float p[E_NUM], se = 0.f;
    #pragma unroll
    for (int e = 0; e < E_NUM; ++e) { p[e] = expf(lg[e] - mx); se += p[e]; }
    const float inv = 1.f / se;

    // top-2, jax tie-break (lower index wins on equal)
    int e0 = 0;
    #pragma unroll
    for (int e = 1; e < E_NUM; ++e) if (lg[e] > lg[e0]) e0 = e;
    int e1 = (e0 == 0) ? 1 : 0;
    #pragma unroll
    for (int e = 0; e < E_NUM; ++e) if (e != e0 && lg[e] > lg[e1]) e1 = e;
    const float pp = expf(lg[e1] - lg[e0]);      // <= 1
    const float w0 = 1.f / (1.f + pp);
    const float w1 = pp / (1.f + pp);

    ws->sel[n*2+0] = e0; ws->sel[n*2+1] = e1;
    ws->wsel[n*2+0] = w0; ws->wsel[n*2+1] = w1;
    #pragma unroll
    for (int e = 0; e < E_NUM; ++e) atomicAdd(&swL[e], p[e]*inv);
    atomicAdd(&scL[e0], 1.f); atomicAdd(&scL[e1], 1.f);
    atomicAdd(&cntL[e0], 1);  atomicAdd(&cntL[e1], 1);
  }
  __syncthreads();
  if (t < E_NUM) {
    atomicAdd(&ws->Sw[t], swL[t]);
    atomicAdd(&ws->Sc[t], scL[t]);
    atomicAdd(&ws->cnt[t], cntL[t]);
  }
}

// ---------------- routing helpers ----------------
__global__ void init_perm_kernel(Ws* __restrict__ ws) {
  const int i = blockIdx.x * 256 + threadIdx.x;
  if (i < PAD_CAP) ws->perm_token[i] = -1;
}

__global__ void scan_kernel(Ws* __restrict__ ws) {
  if (threadIdx.x == 0 && blockIdx.x == 0) {
    int off = 0, nt = 0;
    for (int e = 0; e < E_NUM; ++e) {
      ws->pad_off[e] = off;
      ws->cursor[e]  = 0;
      const int tiles = (ws->cnt[e] + TM - 1) / TM;
      for (int j = 0; j < tiles; ++j) ws->tile_expert[nt++] = e;
      off += tiles * TM;
    }
    ws->pad_off[E_NUM] = off;
    ws->ntiles = nt;
  }
}

__global__ void scatter_kernel(Ws* __restrict__ ws) {
  const int n = blockIdx.x * 256 + threadIdx.x;
  if (n >= N_TOK) return;
  #pragma unroll
  for (int k = 0; k < 2; ++k) {
    const int e = ws->sel[n*2+k];
    const int pos = atomicAdd(&ws->cursor[e], 1);
    const int slot = ws->pad_off[e] + pos;
    ws->perm_token[slot] = n;
    ws->perm_w[slot]     = ws->wsel[n*2+k];
  }
}

// ---------------- GEMM1: h = silu(Xg @ W1[e] + b1[e])  [tile 128x128, K=D] ----------------
__global__ __launch_bounds__(256) void gemm1_kernel(const float* __restrict__ X,
                                                    const float* __restrict__ W1,
                                                    const float* __restrict__ b1,
                                                    const Ws* __restrict__ ws,
                                                    float* __restrict__ hbuf, int tile0) {
  const int gt = tile0 + blockIdx.x;
  if (gt >= ws->ntiles) return;
  const int e  = ws->tile_expert[gt];
  const int f0 = blockIdx.y * 128;

  __shared__ float As[16][132];   // A transposed (k-major), pad->2-way only
  __shared__ float Bs[16][132];

  const int t  = threadIdx.x;
  const int tx = t & 15, ty = t >> 4;
  const int ar = t >> 2, ac = (t & 3) * 4;   // A: 64 rows/pass x 16 cols
  const int br = t >> 5, bc = (t & 31) * 4;  // B: 8 rows/pass x 128 cols

  const int tok0 = ws->perm_token[gt*TM + ar];
  const int tok1 = ws->perm_token[gt*TM + 64 + ar];
  const float* xr0 = X + (size_t)(tok0 < 0 ? 0 : tok0) * D_DIM + ac;
  const float* xr1 = X + (size_t)(tok1 < 0 ? 0 : tok1) * D_DIM + ac;
  const float* wb  = W1 + (size_t)e * D_DIM * F_DIM + f0 + bc;

  float acc[8][8];
  #pragma unroll
  for (int i = 0; i < 8; ++i)
    #pragma unroll
    for (int j = 0; j < 8; ++j) acc[i][j] = 0.f;

  const float4 z4 = make_float4(0.f, 0.f, 0.f, 0.f);
  float4 pa0, pa1, pb0, pb1;
  pa0 = (tok0 < 0) ? z4 : *(const float4*)(xr0);
  pa1 = (tok1 < 0) ? z4 : *(const float4*)(xr1);
  pb0 = *(const float4*)(wb + (size_t)(br    ) * F_DIM);
  pb1 = *(const float4*)(wb + (size_t)(br + 8) * F_DIM);

  const int NKT = D_DIM / 16;
  for (int kt = 0; kt < NKT; ++kt) {
    __syncthreads();
    As[ac+0][ar] = pa0.x; As[ac+1][ar] = pa0.y; As[ac+2][ar] = pa0.z; As[ac+3][ar] = pa0.w;
    As[ac+0][64+ar] = pa1.x; As[ac+1][64+ar] = pa1.y; As[ac+2][64+ar] = pa1.z; As[ac+3][64+ar] = pa1.w;
    *(float4*)&Bs[br  ][bc] = pb0;
    *(float4*)&Bs[br+8][bc] = pb1;
    __syncthreads();
    if (kt + 1 < NKT) {                       // prefetch next K-slice into regs
      const int k0 = (kt + 1) * 16;
      pa0 = (tok0 < 0) ? z4 : *(const float4*)(xr0 + k0);
      pa1 = (tok1 < 0) ? z4 : *(const float4*)(xr1 + k0);
      pb0 = *(const float4*)(wb + (size_t)(k0 + br    ) * F_DIM);
      pb1 = *(const float4*)(wb + (size_t)(k0 + br + 8) * F_DIM);
    }
    #pragma unroll
    for (int k = 0; k < 16; ++k) {
      const float4 a0 = *(const float4*)&As[k][ty*4];
      const float4 a1 = *(const float4*)&As[k][64 + ty*4];
      const float4 b0 = *(const float4*)&Bs[k][tx*4];
      const float4 b1v = *(const float4*)&Bs[k][64 + tx*4];
      const float av[8] = {a0.x,a0.y,a0.z,a0.w,a1.x,a1.y,a1.z,a1.w};
      const float bv[8] = {b0.x,b0.y,b0.z,b0.w,b1v.x,b1v.y,b1v.z,b1v.w};
      #pragma unroll
      for (int i = 0; i < 8; ++i)
        #pragma unroll
        for (int j = 0; j < 8; ++j) acc[i][j] += av[i] * bv[j];
    }
  }

  float bb[8];
  *(float4*)&bb[0] = *(const float4*)(b1 + (size_t)e*F_DIM + f0 + tx*4);
  *(float4*)&bb[4] = *(const float4*)(b1 + (size_t)e*F_DIM + f0 + 64 + tx*4);
  #pragma unroll
  for (int i = 0; i < 8; ++i) {
    const int row = (i >> 2)*64 + ty*4 + (i & 3);
    float* hr = hbuf + (size_t)(blockIdx.x*TM + row) * F_DIM + f0;
    #pragma unroll
    for (int jh = 0; jh < 2; ++jh) {
      float4 v;
      v.x = silu_f(acc[i][jh*4+0] + bb[jh*4+0]);
      v.y = silu_f(acc[i][jh*4+1] + bb[jh*4+1]);
      v.z = silu_f(acc[i][jh*4+2] + bb[jh*4+2]);
      v.w = silu_f(acc[i][jh*4+3] + bb[jh*4+3]);
      *(float4*)(hr + jh*64 + tx*4) = v;
    }
  }
}

// ---------------- GEMM2: out += w * (h @ W2[e] + b2[e])  [tile 128x64, K=F] ----------------
__global__ __launch_bounds__(256) void gemm2_kernel(const float* __restrict__ W2,
                                                    const float* __restrict__ b2,
                                                    const Ws* __restrict__ ws,
                                                    const float* __restrict__ hbuf,
                                                    float* __restrict__ out, int tile0) {
  const int gt = tile0 + blockIdx.x;
  if (gt >= ws->ntiles) return;
  const int e  = ws->tile_expert[gt];
  const int d0 = blockIdx.y * 64;

  __shared__ float As[16][132];
  __shared__ float Bs[16][68];

  const int t  = threadIdx.x;
  const int tx = t & 15, ty = t >> 4;
  const int ar = t >> 2,  ac  = (t & 3) * 4;   // A: 64 rows/pass x 16 cols
  const int br = t >> 4,  bcc = (t & 15) * 4;  // B: 16 rows x 64 cols

  const float* ha  = hbuf + (size_t)(blockIdx.x * TM) * F_DIM;
  const float* xr0 = ha + (size_t)(ar     ) * F_DIM + ac;
  const float* xr1 = ha + (size_t)(ar + 64) * F_DIM + ac;
  const float* wb  = W2 + (size_t)e * F_DIM * D_DIM + d0 + bcc;

  float acc[8][4];
  #pragma unroll
  for (int i = 0; i < 8; ++i)
    #pragma unroll
    for (int j = 0; j < 4; ++j) acc[i][j] = 0.f;

  float4 pa0, pa1, pb;
  pa0 = *(const float4*)(xr0);
  pa1 = *(const float4*)(xr1);
  pb  = *(const float4*)(wb + (size_t)br * D_DIM);

  const int NKT = F_DIM / 16;
  for (int kt = 0; kt < NKT; ++kt) {
    __syncthreads();
    As[ac+0][ar] = pa0.x; As[ac+1][ar] = pa0.y; As[ac+2][ar] = pa0.z; As[ac+3][ar] = pa0.w;
    As[ac+0][64+ar] = pa1.x; As[ac+1][64+ar] = pa1.y; As[ac+2][64+ar] = pa1.z; As[ac+3][64+ar] = pa1.w;
    *(float4*)&Bs[br][bcc] = pb;
    __syncthreads();
    if (kt + 1 < NKT) {
      const int k0 = (kt + 1) * 16;
      pa0 = *(const float4*)(xr0 + k0);
      pa1 = *(const float4*)(xr1 + k0);
      pb  = *(const float4*)(wb + (size_t)(k0 + br) * D_DIM);
    }
    #pragma unroll
    for (int k = 0; k < 16; ++k) {
      const float4 a0 = *(const float4*)&As[k][ty*4];
      const float4 a1 = *(const float4*)&As[k][64 + ty*4];
      const float4 b0 = *(const float4*)&Bs[k][tx*4];
      const float av[8] = {a0.x,a0.y,a0.z,a0.w,a1.x,a1.y,a1.z,a1.w};
      const float bv[4] = {b0.x,b0.y,b0.z,b0.w};
      #pragma unroll
      for (int i = 0; i < 8; ++i)
        #pragma unroll
        for (int j = 0; j < 4; ++j) acc[i][j] += av[i] * bv[j];
    }
  }

  float bb[4];
  *(float4*)&bb[0] = *(const float4*)(b2 + (size_t)e*D_DIM + d0 + tx*4);
  #pragma unroll
  for (int i = 0; i < 8; ++i) {
    const int row  = (i >> 2)*64 + ty*4 + (i & 3);
    const int slot = gt*TM + row;
    const int tok  = ws->perm_token[slot];
    if (tok < 0) continue;
    const float wgt = ws->perm_w[slot];
    float* orow = out + (size_t)tok * D_DIM + d0;
    #pragma unroll
    for (int j = 0; j < 4; ++j)
      atomicAdd(orow + tx*4 + j, wgt * (acc[i][j] + bb[j]));
  }
}

// ---------------- aux loss ----------------
__global__ void finalize_kernel(const Ws* __restrict__ ws, float* __restrict__ out) {
  if (threadIdx.x == 0 && blockIdx.x == 0) {
    float s = 0.f;
    for (int e = 0; e < E_NUM; ++e)
      s += (ws->Sw[e] / (float)N_TOK) * (ws->Sc[e] / (float)N_TOK);
    out[(size_t)N_TOK * D_DIM] = s;   // * E / E * LB_WEIGHT(=1)
  }
}

// ---------------- launch ----------------
extern "C" void kernel_launch(void* const* d_in, const int* in_sizes, int n_in,
                              void* d_out, int out_size, void* d_ws, size_t ws_size,
                              hipStream_t stream) {
  const float* X       = (const float*)d_in[0];
  const float* task    = (const float*)d_in[1];
  const float* Wg_in   = (const float*)d_in[2];
  const float* bg_in   = (const float*)d_in[3];
  const float* Wg_task = (const float*)d_in[4];
  const float* bg_task = (const float*)d_in[5];
  const float* alpha   = (const float*)d_in[6];
  const float* W1      = (const float*)d_in[7];
  const float* b1      = (const float*)d_in[8];
  const float* W2      = (const float*)d_in[9];
  const float* b2      = (const float*)d_in[10];
  float* out = (float*)d_out;
  Ws* ws = (Ws*)d_ws;

  const size_t hoff = (sizeof(Ws) + 255) & ~(size_t)255;
  const size_t avail = (ws_size > hoff) ? (ws_size - hoff) : 0;
  int tpc = (int)(avail / ((size_t)TM * F_DIM * sizeof(float)));  // tiles per h-chunk
  if (tpc < 1) tpc = 1;
  if (tpc > MAX_TILES) tpc = MAX_TILES;
  float* hbuf = (float*)((char*)d_ws + hoff);

  hipMemsetAsync(d_out, 0, (size_t)N_TOK * D_DIM * sizeof(float), stream);
  setup_kernel<<<1, 256, 0, stream>>>(task, Wg_task, bg_task, ws);
  gate_kernel<<<N_TOK/4, 256, 0, stream>>>(X, Wg_in, bg_in, alpha, ws);
  init_perm_kernel<<<(PAD_CAP + 255)/256, 256, 0, stream>>>(ws);
  scan_kernel<<<1, 64, 0, stream>>>(ws);
  scatter_kernel<<<(N_TOK + 255)/256, 256, 0, stream>>>(ws);
  for (int t0 = 0; t0 < MAX_TILES; t0 += tpc) {
    gemm1_kernel<<<dim3(tpc, F_DIM/128), 256, 0, stream>>>(X, W1, b1, ws, hbuf, t0);
    gemm2_kernel<<<dim3(tpc, D_DIM/64), 256, 0, stream>>>(W2, b2, ws, hbuf, out, t0);
  }
  finalize_kernel<<<1, 64, 0, stream>>>(ws, out);
}